// Round 2
// baseline (461.094 us; speedup 1.0000x reference)
//
#include <hip/hip_runtime.h>

typedef unsigned short ushort_t;
typedef __bf16 bf16x8 __attribute__((ext_vector_type(8)));
typedef unsigned short ushort8_t __attribute__((ext_vector_type(8)));
typedef unsigned short ushort4_t __attribute__((ext_vector_type(4)));
typedef float floatx4 __attribute__((ext_vector_type(4)));
typedef unsigned int uint4_t __attribute__((ext_vector_type(4)));
typedef unsigned int uint2_t __attribute__((ext_vector_type(2)));

__device__ __forceinline__ ushort_t f2bf(float f) {
    unsigned int u = __float_as_uint(f);
    u += 0x7FFFu + ((u >> 16) & 1u);  // RNE
    return (ushort_t)(u >> 16);
}
__device__ __forceinline__ float bf2f(ushort_t b) {
    return __uint_as_float(((unsigned int)b) << 16);
}
__device__ __forceinline__ bf16x8 ld_frag(const ushort_t* p) {
    ushort8_t u = *(const ushort8_t*)p;
    return __builtin_bit_cast(bf16x8, u);
}
__device__ __forceinline__ unsigned pack_trunc(float lo, float hi) {
    return __builtin_amdgcn_perm(__float_as_uint(hi), __float_as_uint(lo), 0x07060302u);
}
__device__ __forceinline__ floatx4 mfma16(bf16x8 a, bf16x8 b, floatx4 c) {
    return __builtin_amdgcn_mfma_f32_16x16x32_bf16(a, b, c, 0, 0, 0);
}
// async global->LDS, 16B per lane; LDS dest = wave-uniform base + lane*16
__device__ __forceinline__ void async16(const ushort_t* g, ushort_t* l) {
    __builtin_amdgcn_global_load_lds((const __attribute__((address_space(1))) void*)g,
                                     (__attribute__((address_space(3))) void*)l, 16, 0, 0);
}
// dst.high32lanes <-> src.low32lanes (both regs updated)
__device__ __forceinline__ void pl32swap(unsigned& a, unsigned& b) {
    asm volatile("v_permlane32_swap_b32 %0, %1" : "+v"(a), "+v"(b));
}
// dst odd 16-rows <-> src even 16-rows (both regs updated)
__device__ __forceinline__ void pl16swap(unsigned& a, unsigned& b) {
    asm volatile("v_permlane16_swap_b32 %0, %1" : "+v"(a), "+v"(b));
}

// ---------------- fp32 -> bf16 convert, two sources in one launch ----------------
__global__ __launch_bounds__(256) void cvt_dual(const float* __restrict__ s1,
                                                ushort_t* __restrict__ d1, int n1,
                                                const float* __restrict__ s2,
                                                ushort_t* __restrict__ d2, int n2) {
    int idx = blockIdx.x * 256 + threadIdx.x;
    const float* src;
    ushort_t* dst;
    if (idx < n1) {
        src = s1; dst = d1;
    } else {
        idx -= n1;
        if (idx >= n2) return;
        src = s2; dst = d2;
    }
    const float4* s = (const float4*)src + (size_t)idx * 2;
    float4 a = s[0], b = s[1];
    ushort8_t v;
    v[0] = f2bf(a.x); v[1] = f2bf(a.y); v[2] = f2bf(a.z); v[3] = f2bf(a.w);
    v[4] = f2bf(b.x); v[5] = f2bf(b.y); v[6] = f2bf(b.z); v[7] = f2bf(b.w);
    *(ushort8_t*)(dst + (size_t)idx * 8) = v;
}

// ---------------- GEMM: C[M,N] = A[M,K]*B[N,K]^T, K=1024 compile-time ----------------
template <int MODE>
__global__ __launch_bounds__(256) void gemm_a(const ushort_t* __restrict__ A,
                                              const ushort_t* __restrict__ B,
                                              const float* __restrict__ bias,
                                              void* __restrict__ Cout,
                                              ushort_t* __restrict__ vt,
                                              int M, int N) {
    constexpr int K = 1024;
    __shared__ __attribute__((aligned(16))) ushort_t As[128 * 32];
    __shared__ __attribute__((aligned(16))) ushort_t Bs[128 * 32];
    const int tid = threadIdx.x;
    const int lane = tid & 63, wave = tid >> 6;
    const int quad = lane >> 4, l16 = lane & 15;
    const int wm = wave & 1, wn = wave >> 1;
    const int m0 = blockIdx.y * 128, n0 = blockIdx.x * 128;

    const ushort_t* ga = A + (size_t)(m0 + wave * 32 + (lane >> 2)) * K + (lane & 3) * 8;
    const ushort_t* gb = B + (size_t)(n0 + wave * 32 + (lane >> 2)) * K + (lane & 3) * 8;
    const ushort_t* ga2 = ga + 16 * K;
    const ushort_t* gb2 = gb + 16 * K;
    ushort_t* la = As + wave * 1024;
    ushort_t* lb = Bs + wave * 1024;

    floatx4 acc[4][4] = {};

#pragma unroll
    for (int k0 = 0; k0 < K; k0 += 32) {
        __syncthreads();
        async16(ga + k0, la);
        async16(ga2 + k0, la + 512);
        async16(gb + k0, lb);
        async16(gb2 + k0, lb + 512);
        __syncthreads();

        bf16x8 af[4], bfr[4];
#pragma unroll
        for (int mt = 0; mt < 4; ++mt)
            af[mt] = ld_frag(&As[(wm * 64 + mt * 16 + l16) * 32 + quad * 8]);
#pragma unroll
        for (int nt = 0; nt < 4; ++nt)
            bfr[nt] = ld_frag(&Bs[(wn * 64 + nt * 16 + l16) * 32 + quad * 8]);
#pragma unroll
        for (int mt = 0; mt < 4; ++mt)
#pragma unroll
            for (int nt = 0; nt < 4; ++nt)
                acc[mt][nt] = mfma16(af[mt], bfr[nt], acc[mt][nt]);
    }

    if constexpr (MODE == 2) {
        // fused RoPE on q/k heads (wave spans exactly one 64-wide head)
        if (n0 + wn * 64 < 2048) {
            float afreq = exp2f((float)l16 * (-10.0f / 15.0f));
#pragma unroll
            for (int mt = 0; mt < 4; ++mt) {
                int rowb = m0 + wm * 64 + mt * 16 + quad * 4;
#pragma unroll
                for (int r = 0; r < 4; ++r) {
                    int t = (rowb + r) & 2047;
                    float th = (float)t * afreq;
                    float sn, cs;
                    __sincosf(th, &sn, &cs);
                    float q1 = acc[mt][0][r], q2 = acc[mt][2][r];
                    acc[mt][0][r] = q1 * cs + q2 * sn;
                    acc[mt][2][r] = -q1 * sn + q2 * cs;
                }
            }
        }
    }

#pragma unroll
    for (int mt = 0; mt < 4; ++mt) {
        int row = m0 + wm * 64 + mt * 16 + quad * 4;
#pragma unroll
        for (int nt = 0; nt < 4; ++nt) {
            int nglob = n0 + wn * 64 + nt * 16 + l16;
            if constexpr (MODE == 0) {
                float bv = bias ? bias[nglob] : 0.0f;
#pragma unroll
                for (int r = 0; r < 4; ++r)
                    ((float*)Cout)[(size_t)(row + r) * N + nglob] = acc[mt][nt][r] + bv;
            } else {
                if (nglob < 2048) {
#pragma unroll
                    for (int r = 0; r < 4; ++r)
                        ((ushort_t*)Cout)[(size_t)(row + r) * 2048 + nglob] =
                            f2bf(acc[mt][nt][r]);
                } else {
                    int d = nglob & 63, hh = (nglob >> 6) & 15;
                    int bb = row >> 11, t = row & 2047;
                    ushort4_t pk;
                    pk.x = f2bf(acc[mt][nt][0]);
                    pk.y = f2bf(acc[mt][nt][1]);
                    pk.z = f2bf(acc[mt][nt][2]);
                    pk.w = f2bf(acc[mt][nt][3]);
                    *(ushort4_t*)&vt[(((size_t)bb * 16 + hh) * 64 + d) * 2048 + t] = pk;
                }
            }
        }
    }
}

// ---------------- Flash attention ----------------
// Round 2: back to LDS-staged K/V (round-0 structure; barriers provide latency
// hiding).  Pw LDS transpose buffer ELIMINATED via in-register P transpose
// (permlane32_swap + permlane16_swap compose the 4x4 dword lane-transpose).
// LDS 68.6KB -> 33.8KB, grid 512 -> 1024 one-phase blocks, launch_bounds(256,4)
// => 4 blocks/CU (2x the waves/SIMD of round 0).
#define ATT_SCALE 0.18033688011112042f /* 0.125 * log2(e) */

template <bool DIAG>
__device__ __forceinline__ void attn_step(
    const ushort_t* __restrict__ Ks, const ushort_t* __restrict__ Vt,
    const bf16x8 (&qf)[2][2], floatx4 (&o)[2][4], floatx4 (&lac)[2], float (&m_)[2],
    int quad, int l16, int sw8, int mhi, int qrel) {
    ushort8_t ou;
#pragma unroll
    for (int j = 0; j < 8; ++j) ou[j] = 0x3F80;
    const bf16x8 vONE = __builtin_bit_cast(bf16x8, ou);

    // ---- QK^T from LDS-staged K ----
    floatx4 s[8][2];
    __builtin_amdgcn_s_setprio(1);
#pragma unroll
    for (int mt = 0; mt < 8; ++mt) {
        if (DIAG && mt > mhi) continue;
        const ushort_t* kr = &Ks[(mt * 16 + l16) * 64];
        bf16x8 k0 = ld_frag(kr + ((quad * 8) ^ sw8));
        bf16x8 k1 = ld_frag(kr + ((32 + quad * 8) ^ sw8));
#pragma unroll
        for (int nt = 0; nt < 2; ++nt) {
            floatx4 z = {};
            z = mfma16(k0, qf[nt][0], z);
            s[mt][nt] = mfma16(k1, qf[nt][1], z);
        }
    }
    __builtin_amdgcn_s_setprio(0);

    if (DIAG) {
#pragma unroll
        for (int mt = 0; mt < 8; ++mt) {
            if (mt > mhi) continue;
#pragma unroll
            for (int nt = 0; nt < 2; ++nt)
#pragma unroll
                for (int r = 0; r < 4; ++r)
                    if (mt * 16 + quad * 4 + r > qrel + nt * 16 + l16)
                        s[mt][nt][r] = -3e38f;
        }
    }

    // ---- online softmax with defer-max (T13) ----
    float mx[2];
#pragma unroll
    for (int nt = 0; nt < 2; ++nt) {
        float m0 = -3e38f;
#pragma unroll
        for (int mt = 0; mt < 8; ++mt) {
            if (DIAG && mt > mhi) continue;
            m0 = fmaxf(m0, fmaxf(fmaxf(s[mt][nt][0], s[mt][nt][1]),
                                 fmaxf(s[mt][nt][2], s[mt][nt][3])));
        }
        m0 = fmaxf(m0, __shfl_xor(m0, 16));
        m0 = fmaxf(m0, __shfl_xor(m0, 32));
        mx[nt] = m0;
    }
    bool resc = !__all((mx[0] - m_[0] <= 8.0f) && (mx[1] - m_[1] <= 8.0f));
    if (resc) {
        float alpha_l[2];
#pragma unroll
        for (int nt = 0; nt < 2; ++nt) {
            float mnew = fmaxf(m_[nt], mx[nt]);
            alpha_l[nt] = __builtin_amdgcn_exp2f(m_[nt] - mnew);
            m_[nt] = mnew;
        }
#pragma unroll
        for (int mtq = 0; mtq < 2; ++mtq)
#pragma unroll
            for (int r = 0; r < 4; ++r) {
                float ao = __shfl(alpha_l[mtq], quad * 4 + r);
                lac[mtq][r] *= ao;
#pragma unroll
                for (int ntd = 0; ntd < 4; ++ntd) o[mtq][ntd][r] *= ao;
            }
    }
#pragma unroll
    for (int nt = 0; nt < 2; ++nt)
#pragma unroll
        for (int mt = 0; mt < 8; ++mt) {
            if (DIAG && mt > mhi) continue;
#pragma unroll
            for (int r = 0; r < 4; ++r)
                s[mt][nt][r] = __builtin_amdgcn_exp2f(s[mt][nt][r] - m_[nt]);
        }

    // ---- in-register P transpose (replaces Pw LDS round-trip) ----
    // lane(quad,l16) holds P[q=nt*16+l16][k=16mt+4quad+r]; A-frag needs
    // P[q=l16][k=32kc+8quad'..+7].  With E=pk[2kc], O=pk[2kc+1]:
    //   pl32swap(E,O); pl16swap(E,O)  ->  E'' = frag dwords 0,1 ; O'' = dwords 2,3
    uint2_t pk[2][8];
#pragma unroll
    for (int nt = 0; nt < 2; ++nt)
#pragma unroll
        for (int mt = 0; mt < 8; ++mt) {
            if (DIAG && mt > mhi) continue;
            pk[nt][mt].x = pack_trunc(s[mt][nt][0], s[mt][nt][1]);
            pk[nt][mt].y = pack_trunc(s[mt][nt][2], s[mt][nt][3]);
        }

    __builtin_amdgcn_s_setprio(1);
#pragma unroll
    for (int kc = 0; kc < 4; ++kc) {
        if (DIAG && kc > (mhi >> 1)) continue;
        bf16x8 ap[2];
#pragma unroll
        for (int nt = 0; nt < 2; ++nt) {
            unsigned a0 = pk[nt][2 * kc].x, a1 = pk[nt][2 * kc].y;
            unsigned b0 = pk[nt][2 * kc + 1].x, b1 = pk[nt][2 * kc + 1].y;
            pl32swap(a0, b0);
            pl16swap(a0, b0);
            pl32swap(a1, b1);
            pl16swap(a1, b1);
            uint4_t ud;
            ud[0] = a0; ud[1] = a1; ud[2] = b0; ud[3] = b1;
            ap[nt] = __builtin_bit_cast(bf16x8, ud);
        }
        lac[0] = mfma16(ap[0], vONE, lac[0]);
        lac[1] = mfma16(ap[1], vONE, lac[1]);
#pragma unroll
        for (int ntd = 0; ntd < 4; ++ntd) {
            bf16x8 bv = ld_frag(&Vt[(ntd * 16 + l16) * 136 + kc * 32 + quad * 8]);
            o[0][ntd] = mfma16(ap[0], bv, o[0][ntd]);
            o[1][ntd] = mfma16(ap[1], bv, o[1][ntd]);
        }
    }
    __builtin_amdgcn_s_setprio(0);
}

__global__ __launch_bounds__(256, 4) void attn_kernel(const ushort_t* __restrict__ qk,
                                                      const ushort_t* __restrict__ vt,
                                                      ushort_t* __restrict__ y) {
    __shared__ __attribute__((aligned(16))) ushort_t Ks[128 * 64];   // 16 KB
    __shared__ __attribute__((aligned(16))) ushort_t Vt[64 * 136];   // 17 KB

    const int tid = threadIdx.x, lane = tid & 63, w = tid >> 6;
    const int quad = lane >> 4, l16 = lane & 15;
    const int lrow = lane >> 3, lchunk = lane & 7;
    const int sw8 = 8 * (l16 >> 1);

    // 1024 one-phase blocks: idx = rank*64 + bh.  jj table balances the 4
    // resident blocks per CU (rank groups {r,r+4,r+8,r+12} each sum to 30),
    // and bh in the low 6 bits keeps a head's 16 blocks on one XCD (idx%8).
    const int idx = (int)blockIdx.x;
    const int rank = idx >> 6, bh = idx & 63;
    constexpr int jj_tab[16] = {15, 13, 11, 9, 0, 2, 4, 6, 14, 12, 10, 8, 1, 3, 5, 7};
    const int jj = jj_tab[rank];
    const int b = bh >> 4, h = bh & 15;

    const ushort_t* base_k = qk + (size_t)(b * 2048) * 2048 + 1024 + h * 64;
    const ushort_t* base_v = vt + (size_t)bh * 64 * 2048;
    const int vd = w * 4 + (lane >> 4);
    const int vc8 = lane & 15;

    ushort8_t kreg[4], vreg[4];
    auto load_kv = [&](int kt) {
        const ushort_t* gk = base_k + (size_t)(kt * 128) * 2048 + lchunk * 8;
#pragma unroll
        for (int i = 0; i < 4; ++i)
            kreg[i] = *(const ushort8_t*)(gk + (size_t)(w * 32 + i * 8 + lrow) * 2048);
        const ushort_t* gv = base_v + kt * 128;
#pragma unroll
        for (int i = 0; i < 4; ++i)
            vreg[i] = *(const ushort8_t*)(gv + (size_t)(i * 16 + vd) * 2048 + vc8 * 8);
    };
    auto store_kv = [&]() {
#pragma unroll
        for (int i = 0; i < 4; ++i) {
            int row = w * 32 + i * 8 + lrow;
            *(ushort8_t*)&Ks[row * 64 + 8 * (lchunk ^ ((row >> 1) & 7))] = kreg[i];
        }
#pragma unroll
        for (int i = 0; i < 4; ++i)
            *(ushort8_t*)&Vt[(i * 16 + vd) * 136 + vc8 * 8] = vreg[i];
    };

    const int q0 = jj * 128 + w * 32;

    bf16x8 qf[2][2];
    {
        const ushort_t* qb = qk + (size_t)(b * 2048 + q0) * 2048 + h * 64 + quad * 8;
#pragma unroll
        for (int nt = 0; nt < 2; ++nt)
#pragma unroll
            for (int kd = 0; kd < 2; ++kd) {
                ushort8_t raw =
                    *(const ushort8_t*)(qb + (size_t)(nt * 16 + l16) * 2048 + kd * 32);
                uint4_t dw;
#pragma unroll
                for (int jx = 0; jx < 4; ++jx) {
                    float f0 = bf2f(raw[2 * jx]) * ATT_SCALE;
                    float f1 = bf2f(raw[2 * jx + 1]) * ATT_SCALE;
                    dw[jx] = pack_trunc(f0, f1);
                }
                qf[nt][kd] = __builtin_bit_cast(bf16x8, dw);
            }
    }

    floatx4 o[2][4] = {};
    floatx4 lac[2] = {};
    float m_[2] = {-3e38f, -3e38f};

    load_kv(0);
#pragma unroll 1
    for (int kt = 0; kt <= jj; ++kt) {
        __syncthreads();
        store_kv();
        __syncthreads();
        if (kt < jj) load_kv(kt + 1);

        if (kt < jj)
            attn_step<false>(Ks, Vt, qf, o, lac, m_, quad, l16, sw8, 7, 0);
        else
            attn_step<true>(Ks, Vt, qf, o, lac, m_, quad, l16, sw8, 2 * w + 1, w * 32);
    }

    ushort_t* yb = y + (size_t)(b * 2048 + q0) * 1024 + h * 64;
#pragma unroll
    for (int mtq = 0; mtq < 2; ++mtq)
#pragma unroll
        for (int r = 0; r < 4; ++r) {
            float inv = 1.0f / lac[mtq][r];
            int row = mtq * 16 + quad * 4 + r;
#pragma unroll
            for (int ntd = 0; ntd < 4; ++ntd)
                yb[(size_t)row * 1024 + ntd * 16 + l16] = f2bf(o[mtq][ntd][r] * inv);
        }
}

extern "C" void kernel_launch(void* const* d_in, const int* in_sizes, int n_in,
                              void* d_out, int out_size, void* d_ws, size_t ws_size,
                              hipStream_t stream) {
    const float* x = (const float*)d_in[0];
    const float* qkv_w = (const float*)d_in[1];
    const float* c_proj_w = (const float*)d_in[2];
    const float* c_proj_b = (const float*)d_in[3];
    float* out = (float*)d_out;

    const int M = 8192;  // B*T

    // Memory plan (time-multiplexed):
    //   d_out (32MB fp32): xb bf16 [8192x1024] during gemm1 (dead after);
    //                      final fp32 output written by gemm2 (full overwrite).
    //   ws[0,32M):  qk bf16 [8192 x 2048]       (gemm1 -> attn)
    //   ws[32,48M): vt bf16 [4][16][64][2048]   (gemm1 -> attn); first 2MB reused
    //               as wpb (c_proj_w bf16) after attn
    //   ws[48,64M): wb bf16 [3072x1024] (qkv_w) during gemm1 (dead after);
    //               y bf16 [8192x1024] written by attn (overwrites wb)
    ushort_t* qk = (ushort_t*)d_ws;
    ushort_t* vt = (ushort_t*)((char*)d_ws + (size_t)33554432);
    ushort_t* wpb = vt;
    ushort_t* wb = (ushort_t*)((char*)d_ws + (size_t)50331648);
    ushort_t* y = wb;
    ushort_t* xb = (ushort_t*)d_out;

    cvt_dual<<<dim3(5632), 256, 0, stream>>>(x, xb, M * 1024 / 8,
                                             qkv_w, wb, 3072 * 1024 / 8);

    gemm_a<2><<<dim3(3072 / 128, M / 128), 256, 0, stream>>>(
        xb, wb, nullptr, qk, vt, M, 3072);

    attn_kernel<<<dim3(1024), 256, 0, stream>>>(qk, vt, y);

    cvt_dual<<<dim3(512), 256, 0, stream>>>(c_proj_w, wpb, 1024 * 1024 / 8,
                                            nullptr, nullptr, 0);

    gemm_a<0><<<dim3(1024 / 128, M / 128), 256, 0, stream>>>(
        y, wpb, c_proj_b, out, nullptr, M, 1024);
}

// Round 3
// 254.450 us; speedup vs baseline: 1.8121x; 1.8121x over previous
//
#include <hip/hip_runtime.h>

typedef unsigned short ushort_t;
typedef __bf16 bf16x8 __attribute__((ext_vector_type(8)));
typedef unsigned short ushort8_t __attribute__((ext_vector_type(8)));
typedef unsigned short ushort4_t __attribute__((ext_vector_type(4)));
typedef float floatx4 __attribute__((ext_vector_type(4)));
typedef unsigned int uint4_t __attribute__((ext_vector_type(4)));
typedef unsigned int uint2_t __attribute__((ext_vector_type(2)));

__device__ __forceinline__ ushort_t f2bf(float f) {
    unsigned int u = __float_as_uint(f);
    u += 0x7FFFu + ((u >> 16) & 1u);  // RNE
    return (ushort_t)(u >> 16);
}
__device__ __forceinline__ float bf2f(ushort_t b) {
    return __uint_as_float(((unsigned int)b) << 16);
}
__device__ __forceinline__ bf16x8 ld_frag(const ushort_t* p) {
    ushort8_t u = *(const ushort8_t*)p;
    return __builtin_bit_cast(bf16x8, u);
}
__device__ __forceinline__ unsigned pack_trunc(float lo, float hi) {
    return __builtin_amdgcn_perm(__float_as_uint(hi), __float_as_uint(lo), 0x07060302u);
}
__device__ __forceinline__ floatx4 mfma16(bf16x8 a, bf16x8 b, floatx4 c) {
    return __builtin_amdgcn_mfma_f32_16x16x32_bf16(a, b, c, 0, 0, 0);
}
// async global->LDS, 16B per lane; LDS dest = wave-uniform base + lane*16
__device__ __forceinline__ void async16(const ushort_t* g, ushort_t* l) {
    __builtin_amdgcn_global_load_lds((const __attribute__((address_space(1))) void*)g,
                                     (__attribute__((address_space(3))) void*)l, 16, 0, 0);
}

// ---------------- fp32 -> bf16 convert, two sources in one launch ----------------
__global__ __launch_bounds__(256) void cvt_dual(const float* __restrict__ s1,
                                                ushort_t* __restrict__ d1, int n1,
                                                const float* __restrict__ s2,
                                                ushort_t* __restrict__ d2, int n2) {
    int idx = blockIdx.x * 256 + threadIdx.x;
    const float* src;
    ushort_t* dst;
    if (idx < n1) {
        src = s1; dst = d1;
    } else {
        idx -= n1;
        if (idx >= n2) return;
        src = s2; dst = d2;
    }
    const float4* s = (const float4*)src + (size_t)idx * 2;
    float4 a = s[0], b = s[1];
    ushort8_t v;
    v[0] = f2bf(a.x); v[1] = f2bf(a.y); v[2] = f2bf(a.z); v[3] = f2bf(a.w);
    v[4] = f2bf(b.x); v[5] = f2bf(b.y); v[6] = f2bf(b.z); v[7] = f2bf(b.w);
    *(ushort8_t*)(dst + (size_t)idx * 8) = v;
}

// ---------------- GEMM: C[M,N] = A[M,K]*B[N,K]^T, K=1024 compile-time ----------------
template <int MODE>
__global__ __launch_bounds__(256) void gemm_a(const ushort_t* __restrict__ A,
                                              const ushort_t* __restrict__ B,
                                              const float* __restrict__ bias,
                                              void* __restrict__ Cout,
                                              ushort_t* __restrict__ vt,
                                              int M, int N) {
    constexpr int K = 1024;
    __shared__ __attribute__((aligned(16))) ushort_t As[128 * 32];
    __shared__ __attribute__((aligned(16))) ushort_t Bs[128 * 32];
    const int tid = threadIdx.x;
    const int lane = tid & 63, wave = tid >> 6;
    const int quad = lane >> 4, l16 = lane & 15;
    const int wm = wave & 1, wn = wave >> 1;
    const int m0 = blockIdx.y * 128, n0 = blockIdx.x * 128;

    const ushort_t* ga = A + (size_t)(m0 + wave * 32 + (lane >> 2)) * K + (lane & 3) * 8;
    const ushort_t* gb = B + (size_t)(n0 + wave * 32 + (lane >> 2)) * K + (lane & 3) * 8;
    const ushort_t* ga2 = ga + 16 * K;
    const ushort_t* gb2 = gb + 16 * K;
    ushort_t* la = As + wave * 1024;
    ushort_t* lb = Bs + wave * 1024;

    floatx4 acc[4][4] = {};

#pragma unroll
    for (int k0 = 0; k0 < K; k0 += 32) {
        __syncthreads();
        async16(ga + k0, la);
        async16(ga2 + k0, la + 512);
        async16(gb + k0, lb);
        async16(gb2 + k0, lb + 512);
        __syncthreads();

        bf16x8 af[4], bfr[4];
#pragma unroll
        for (int mt = 0; mt < 4; ++mt)
            af[mt] = ld_frag(&As[(wm * 64 + mt * 16 + l16) * 32 + quad * 8]);
#pragma unroll
        for (int nt = 0; nt < 4; ++nt)
            bfr[nt] = ld_frag(&Bs[(wn * 64 + nt * 16 + l16) * 32 + quad * 8]);
#pragma unroll
        for (int mt = 0; mt < 4; ++mt)
#pragma unroll
            for (int nt = 0; nt < 4; ++nt)
                acc[mt][nt] = mfma16(af[mt], bfr[nt], acc[mt][nt]);
    }

    if constexpr (MODE == 2) {
        // fused RoPE on q/k heads (wave spans exactly one 64-wide head)
        if (n0 + wn * 64 < 2048) {
            float afreq = exp2f((float)l16 * (-10.0f / 15.0f));
#pragma unroll
            for (int mt = 0; mt < 4; ++mt) {
                int rowb = m0 + wm * 64 + mt * 16 + quad * 4;
#pragma unroll
                for (int r = 0; r < 4; ++r) {
                    int t = (rowb + r) & 2047;
                    float th = (float)t * afreq;
                    float sn, cs;
                    __sincosf(th, &sn, &cs);
                    float q1 = acc[mt][0][r], q2 = acc[mt][2][r];
                    acc[mt][0][r] = q1 * cs + q2 * sn;
                    acc[mt][2][r] = -q1 * sn + q2 * cs;
                }
            }
        }
    }

#pragma unroll
    for (int mt = 0; mt < 4; ++mt) {
        int row = m0 + wm * 64 + mt * 16 + quad * 4;
#pragma unroll
        for (int nt = 0; nt < 4; ++nt) {
            int nglob = n0 + wn * 64 + nt * 16 + l16;
            if constexpr (MODE == 0) {
                float bv = bias ? bias[nglob] : 0.0f;
#pragma unroll
                for (int r = 0; r < 4; ++r)
                    ((float*)Cout)[(size_t)(row + r) * N + nglob] = acc[mt][nt][r] + bv;
            } else {
                if (nglob < 2048) {
#pragma unroll
                    for (int r = 0; r < 4; ++r)
                        ((ushort_t*)Cout)[(size_t)(row + r) * 2048 + nglob] =
                            f2bf(acc[mt][nt][r]);
                } else {
                    int d = nglob & 63, hh = (nglob >> 6) & 15;
                    int bb = row >> 11, t = row & 2047;
                    ushort4_t pk;
                    pk.x = f2bf(acc[mt][nt][0]);
                    pk.y = f2bf(acc[mt][nt][1]);
                    pk.z = f2bf(acc[mt][nt][2]);
                    pk.w = f2bf(acc[mt][nt][3]);
                    *(ushort4_t*)&vt[(((size_t)bb * 16 + hh) * 64 + d) * 2048 + t] = pk;
                }
            }
        }
    }
}

// ---------------- Flash attention ----------------
// Round 3: round-0 structure (LDS-staged K/V, LDS Pw transpose — proven 75us,
// 124 VGPR) with ONE change: Pw is time-split into two 64-wide k-halves
// (write half -> PV on half), shrinking Pw 32x136 -> 32x72 per wave.
// LDS 68608 -> 52224 B  =>  3 blocks/CU instead of 2 (VGPR already allowed 4).
// Grid becomes 1024 single-phase blocks with a balanced jj table so >2
// blocks/CU can actually be resident; idx%8 == bh%8 keeps each head's 16
// blocks on one XCD for K/V L2 reuse.
#define ATT_SCALE 0.18033688011112042f /* 0.125 * log2(e) */

template <bool DIAG>
__device__ __forceinline__ void attn_step(
    const ushort_t* __restrict__ Ks, const ushort_t* __restrict__ Vt,
    ushort_t* __restrict__ Pw, const bf16x8 (&qf)[2][2],
    floatx4 (&o)[2][4], floatx4 (&lac)[2], float (&m_)[2],
    int quad, int l16, int sw8, int mhi, int qrel) {
    ushort8_t ou;
#pragma unroll
    for (int j = 0; j < 8; ++j) ou[j] = 0x3F80;
    const bf16x8 vONE = __builtin_bit_cast(bf16x8, ou);

    // ---- QK^T from LDS-staged K ----
    floatx4 s[8][2];
    __builtin_amdgcn_s_setprio(1);
#pragma unroll
    for (int mt = 0; mt < 8; ++mt) {
        if (DIAG && mt > mhi) continue;
        const ushort_t* kr = &Ks[(mt * 16 + l16) * 64];
        bf16x8 k0 = ld_frag(kr + ((quad * 8) ^ sw8));
        bf16x8 k1 = ld_frag(kr + ((32 + quad * 8) ^ sw8));
#pragma unroll
        for (int nt = 0; nt < 2; ++nt) {
            floatx4 z = {};
            z = mfma16(k0, qf[nt][0], z);
            s[mt][nt] = mfma16(k1, qf[nt][1], z);
        }
    }
    __builtin_amdgcn_s_setprio(0);

    if (DIAG) {
#pragma unroll
        for (int mt = 0; mt < 8; ++mt) {
            if (mt > mhi) continue;
#pragma unroll
            for (int nt = 0; nt < 2; ++nt)
#pragma unroll
                for (int r = 0; r < 4; ++r)
                    if (mt * 16 + quad * 4 + r > qrel + nt * 16 + l16)
                        s[mt][nt][r] = -3e38f;
        }
    }

    // ---- online softmax with defer-max (T13) ----
    float mx[2];
#pragma unroll
    for (int nt = 0; nt < 2; ++nt) {
        float m0 = -3e38f;
#pragma unroll
        for (int mt = 0; mt < 8; ++mt) {
            if (DIAG && mt > mhi) continue;
            m0 = fmaxf(m0, fmaxf(fmaxf(s[mt][nt][0], s[mt][nt][1]),
                                 fmaxf(s[mt][nt][2], s[mt][nt][3])));
        }
        m0 = fmaxf(m0, __shfl_xor(m0, 16));
        m0 = fmaxf(m0, __shfl_xor(m0, 32));
        mx[nt] = m0;
    }
    bool resc = !__all((mx[0] - m_[0] <= 8.0f) && (mx[1] - m_[1] <= 8.0f));
    if (resc) {
        float alpha_l[2];
#pragma unroll
        for (int nt = 0; nt < 2; ++nt) {
            float mnew = fmaxf(m_[nt], mx[nt]);
            alpha_l[nt] = __builtin_amdgcn_exp2f(m_[nt] - mnew);
            m_[nt] = mnew;
        }
#pragma unroll
        for (int mtq = 0; mtq < 2; ++mtq)
#pragma unroll
            for (int r = 0; r < 4; ++r) {
                float ao = __shfl(alpha_l[mtq], quad * 4 + r);
                lac[mtq][r] *= ao;
#pragma unroll
                for (int ntd = 0; ntd < 4; ++ntd) o[mtq][ntd][r] *= ao;
            }
    }
#pragma unroll
    for (int nt = 0; nt < 2; ++nt)
#pragma unroll
        for (int mt = 0; mt < 8; ++mt) {
            if (DIAG && mt > mhi) continue;
#pragma unroll
            for (int r = 0; r < 4; ++r)
                s[mt][nt][r] = __builtin_amdgcn_exp2f(s[mt][nt][r] - m_[nt]);
        }

    // ---- P transpose through per-wave LDS, time-split into two k-halves ----
    // half h covers k in [64h, 64h+64): write P columns, then PV over kc=2h,2h+1.
    // Pw is 32 rows x 72 ushorts (64 data + 8 pad; same bank pattern as 136).
#pragma unroll
    for (int half = 0; half < 2; ++half) {
        if (DIAG && 4 * half > mhi) continue;
#pragma unroll
        for (int mt = 4 * half; mt < 4 * half + 4; ++mt) {
            if (DIAG && mt > mhi) continue;
#pragma unroll
            for (int nt = 0; nt < 2; ++nt) {
                uint2_t pk;
                pk.x = pack_trunc(s[mt][nt][0], s[mt][nt][1]);
                pk.y = pack_trunc(s[mt][nt][2], s[mt][nt][3]);
                *(uint2_t*)&Pw[(nt * 16 + l16) * 72 + (mt - 4 * half) * 16 + quad * 4] =
                    pk;
            }
        }

        __builtin_amdgcn_s_setprio(1);
#pragma unroll
        for (int kc2 = 0; kc2 < 2; ++kc2) {
            const int kc = 2 * half + kc2;
            if (DIAG && kc > (mhi >> 1)) continue;
            bf16x8 ap0 = ld_frag(&Pw[l16 * 72 + kc2 * 32 + quad * 8]);
            bf16x8 ap1 = ld_frag(&Pw[(16 + l16) * 72 + kc2 * 32 + quad * 8]);
            lac[0] = mfma16(ap0, vONE, lac[0]);
            lac[1] = mfma16(ap1, vONE, lac[1]);
#pragma unroll
            for (int ntd = 0; ntd < 4; ++ntd) {
                bf16x8 bv = ld_frag(&Vt[(ntd * 16 + l16) * 136 + kc * 32 + quad * 8]);
                o[0][ntd] = mfma16(ap0, bv, o[0][ntd]);
                o[1][ntd] = mfma16(ap1, bv, o[1][ntd]);
            }
        }
        __builtin_amdgcn_s_setprio(0);
    }
}

__global__ __launch_bounds__(256, 2) void attn_kernel(const ushort_t* __restrict__ qk,
                                                      const ushort_t* __restrict__ vt,
                                                      ushort_t* __restrict__ y) {
    __shared__ __attribute__((aligned(16))) ushort_t Ks[128 * 64];   // 16 KB
    __shared__ __attribute__((aligned(16))) ushort_t Vt[64 * 136];   // 17 KB
    __shared__ __attribute__((aligned(16))) ushort_t Pw_all[4 * 2304];  // 18 KB

    const int tid = threadIdx.x, lane = tid & 63, w = tid >> 6;
    const int quad = lane >> 4, l16 = lane & 15;
    const int lrow = lane >> 3, lchunk = lane & 7;
    const int sw8 = 8 * (l16 >> 1);
    ushort_t* Pw = Pw_all + w * 2304;

    // 1024 one-phase blocks: idx = rank*64 + bh.  jj table balances the
    // resident blocks per CU (rank groups {r,r+4,r+8,r+12} each sum to 34
    // steps), and idx%8 == bh%8 keeps a head's 16 blocks on one XCD.
    const int idx = (int)blockIdx.x;
    const int rank = idx >> 6, bh = idx & 63;
    constexpr int jj_tab[16] = {15, 13, 11, 9, 0, 2, 4, 6, 14, 12, 10, 8, 1, 3, 5, 7};
    const int jj = jj_tab[rank];
    const int b = bh >> 4, h = bh & 15;

    const ushort_t* base_k = qk + (size_t)(b * 2048) * 2048 + 1024 + h * 64;
    const ushort_t* base_v = vt + (size_t)bh * 64 * 2048;
    const int vd = w * 4 + (lane >> 4);
    const int vc8 = lane & 15;

    ushort8_t kreg[4], vreg[4];
    auto load_kv = [&](int kt) {
        const ushort_t* gk = base_k + (size_t)(kt * 128) * 2048 + lchunk * 8;
#pragma unroll
        for (int i = 0; i < 4; ++i)
            kreg[i] = *(const ushort8_t*)(gk + (size_t)(w * 32 + i * 8 + lrow) * 2048);
        const ushort_t* gv = base_v + kt * 128;
#pragma unroll
        for (int i = 0; i < 4; ++i)
            vreg[i] = *(const ushort8_t*)(gv + (size_t)(i * 16 + vd) * 2048 + vc8 * 8);
    };
    auto store_kv = [&]() {
#pragma unroll
        for (int i = 0; i < 4; ++i) {
            int row = w * 32 + i * 8 + lrow;
            *(ushort8_t*)&Ks[row * 64 + 8 * (lchunk ^ ((row >> 1) & 7))] = kreg[i];
        }
#pragma unroll
        for (int i = 0; i < 4; ++i)
            *(ushort8_t*)&Vt[(i * 16 + vd) * 136 + vc8 * 8] = vreg[i];
    };

    const int q0 = jj * 128 + w * 32;

    bf16x8 qf[2][2];
    {
        const ushort_t* qb = qk + (size_t)(b * 2048 + q0) * 2048 + h * 64 + quad * 8;
#pragma unroll
        for (int nt = 0; nt < 2; ++nt)
#pragma unroll
            for (int kd = 0; kd < 2; ++kd) {
                ushort8_t raw =
                    *(const ushort8_t*)(qb + (size_t)(nt * 16 + l16) * 2048 + kd * 32);
                uint4_t dw;
#pragma unroll
                for (int jx = 0; jx < 4; ++jx) {
                    float f0 = bf2f(raw[2 * jx]) * ATT_SCALE;
                    float f1 = bf2f(raw[2 * jx + 1]) * ATT_SCALE;
                    dw[jx] = pack_trunc(f0, f1);
                }
                qf[nt][kd] = __builtin_bit_cast(bf16x8, dw);
            }
    }

    floatx4 o[2][4] = {};
    floatx4 lac[2] = {};
    float m_[2] = {-3e38f, -3e38f};

    load_kv(0);
#pragma unroll 1
    for (int kt = 0; kt <= jj; ++kt) {
        __syncthreads();
        store_kv();
        __syncthreads();
        if (kt < jj) load_kv(kt + 1);

        if (kt < jj)
            attn_step<false>(Ks, Vt, Pw, qf, o, lac, m_, quad, l16, sw8, 7, 0);
        else
            attn_step<true>(Ks, Vt, Pw, qf, o, lac, m_, quad, l16, sw8, 2 * w + 1,
                            w * 32);
    }

    ushort_t* yb = y + (size_t)(b * 2048 + q0) * 1024 + h * 64;
#pragma unroll
    for (int mtq = 0; mtq < 2; ++mtq)
#pragma unroll
        for (int r = 0; r < 4; ++r) {
            float inv = 1.0f / lac[mtq][r];
            int row = mtq * 16 + quad * 4 + r;
#pragma unroll
            for (int ntd = 0; ntd < 4; ++ntd)
                yb[(size_t)row * 1024 + ntd * 16 + l16] = f2bf(o[mtq][ntd][r] * inv);
        }
}

extern "C" void kernel_launch(void* const* d_in, const int* in_sizes, int n_in,
                              void* d_out, int out_size, void* d_ws, size_t ws_size,
                              hipStream_t stream) {
    const float* x = (const float*)d_in[0];
    const float* qkv_w = (const float*)d_in[1];
    const float* c_proj_w = (const float*)d_in[2];
    const float* c_proj_b = (const float*)d_in[3];
    float* out = (float*)d_out;

    const int M = 8192;  // B*T

    // Memory plan (time-multiplexed):
    //   d_out (32MB fp32): xb bf16 [8192x1024] during gemm1 (dead after);
    //                      final fp32 output written by gemm2 (full overwrite).
    //   ws[0,32M):  qk bf16 [8192 x 2048]       (gemm1 -> attn)
    //   ws[32,48M): vt bf16 [4][16][64][2048]   (gemm1 -> attn); first 2MB reused
    //               as wpb (c_proj_w bf16) after attn
    //   ws[48,64M): wb bf16 [3072x1024] (qkv_w) during gemm1 (dead after);
    //               y bf16 [8192x1024] written by attn (overwrites wb)
    ushort_t* qk = (ushort_t*)d_ws;
    ushort_t* vt = (ushort_t*)((char*)d_ws + (size_t)33554432);
    ushort_t* wpb = vt;
    ushort_t* wb = (ushort_t*)((char*)d_ws + (size_t)50331648);
    ushort_t* y = wb;
    ushort_t* xb = (ushort_t*)d_out;

    cvt_dual<<<dim3(5632), 256, 0, stream>>>(x, xb, M * 1024 / 8,
                                             qkv_w, wb, 3072 * 1024 / 8);

    gemm_a<2><<<dim3(3072 / 128, M / 128), 256, 0, stream>>>(
        xb, wb, nullptr, qk, vt, M, 3072);

    attn_kernel<<<dim3(1024), 256, 0, stream>>>(qk, vt, y);

    cvt_dual<<<dim3(512), 256, 0, stream>>>(c_proj_w, wpb, 1024 * 1024 / 8,
                                            nullptr, nullptr, 0);

    gemm_a<0><<<dim3(1024 / 128, M / 128), 256, 0, stream>>>(
        y, wpb, c_proj_b, out, nullptr, M, 1024);
}